// Round 5
// baseline (519.048 us; speedup 1.0000x reference)
//
#include <hip/hip_runtime.h>

// scatter_mean over sorted index: E edges x D=128 features -> N segments.
// Fully fused, NO workspace use (round-3 theory: d_ws overflow corrupted the
// harness's pristine input copy -> post-timing divergence). Each 64-lane wave
// owns one segment: half-wave binary-searches lower_bound(n), other half
// lower_bound(n+1) over the sorted index (uniform-address loads, L2-resident),
// then 2 edge-rows x 32 float4 columns accumulate, shfl-merge, one 512B store.

#define FEAT_D   128
#define FEAT_D4  32   // float4 per row

__global__ __launch_bounds__(256) void scatter_mean_fused(
        const float4* __restrict__ x4,
        const int*    __restrict__ index,
        float4*       __restrict__ out4,
        int E, int N) {
    int l    = threadIdx.x & 63;        // lane within wave
    int wave = threadIdx.x >> 6;        // 0..3
    int n    = blockIdx.x * 4 + wave;   // segment id
    if (n >= N) return;

    int sub  = l >> 5;   // 0: searches n / accumulates even rows; 1: n+1 / odd rows
    int lane = l & 31;   // float4 column

    // parallel lower_bound: half the wave searches target=n, half target=n+1
    int target = n + sub;
    int lo = 0, hi = E;
    while (lo < hi) {
        int mid = (lo + hi) >> 1;
        if (index[mid] < target) lo = mid + 1; else hi = mid;
    }
    int start = __shfl(lo, 0, 64);   // lower_bound(n)
    int end   = __shfl(lo, 32, 64);  // lower_bound(n+1)

    float4 acc = make_float4(0.f, 0.f, 0.f, 0.f);
    for (int e = start + sub; e < end; e += 2) {
        float4 v = x4[(size_t)e * FEAT_D4 + lane];
        acc.x += v.x; acc.y += v.y; acc.z += v.z; acc.w += v.w;
    }

    // merge the two 32-lane halves (width-64 wave)
    acc.x += __shfl_down(acc.x, 32, 64);
    acc.y += __shfl_down(acc.y, 32, 64);
    acc.z += __shfl_down(acc.z, 32, 64);
    acc.w += __shfl_down(acc.w, 32, 64);

    if (sub == 0) {
        int c = end - start;
        float inv = 1.0f / (float)(c > 0 ? c : 1);   // clamp(count, 1)
        acc.x *= inv; acc.y *= inv; acc.z *= inv; acc.w *= inv;
        out4[(size_t)n * FEAT_D4 + lane] = acc;
    }
}

extern "C" void kernel_launch(void* const* d_in, const int* in_sizes, int n_in,
                              void* d_out, int out_size, void* d_ws, size_t ws_size,
                              hipStream_t stream) {
    const float* x     = (const float*)d_in[0];
    const int*   index = (const int*)d_in[1];

    const int E = in_sizes[1];             // 640000
    const int N = out_size / FEAT_D;       // 100000

    int threads = 256;                      // 4 waves -> 4 segments per block
    int blocks  = (N + 3) / 4;
    scatter_mean_fused<<<blocks, threads, 0, stream>>>(
        (const float4*)x, index, (float4*)d_out, E, N);
}

// Round 6
// 461.655 us; speedup vs baseline: 1.1243x; 1.1243x over previous
//
#include <hip/hip_runtime.h>

// scatter_mean over sorted index: E edges x D=128 -> N segments, fp32.
// Round-6 design: block = 64 consecutive segments. Phase 1: 65 parallel
// binary searches -> LDS bounds (amortizes the dependent search chain 64x
// vs round-5's one-search-per-wave). Phase 2: each of 4 waves sweeps 16
// segments; lanes = 4 edge-rows x 16 col-groups, float8 per lane (2
// independent dwordx4 in flight -> 4x edge-load MLP), 2-step shfl_xor merge,
// coalesced 512B row store. No atomics, no workspace, no zero-init pass.

#define SEGS 64
#define D4   32   // float4 per row (D=128)

__global__ __launch_bounds__(256) void scatter_mean_blk(
        const float4* __restrict__ x4,
        const int*    __restrict__ index,
        float4*       __restrict__ out4,
        int E, int N) {
    __shared__ int sOff[SEGS + 1];
    const int base = blockIdx.x * SEGS;
    const int t    = threadIdx.x;

    // Phase 1: parallel lower_bound for targets base..base+SEGS (65 threads)
    for (int tt = t; tt <= SEGS; tt += 256) {
        int target = base + tt;
        int lo = 0, hi = E;
        while (lo < hi) {
            int mid = (lo + hi) >> 1;
            if (index[mid] < target) lo = mid + 1; else hi = mid;
        }
        sOff[tt] = lo;
    }
    __syncthreads();

    // Phase 2: 4 waves sweep the 64 segments round-robin
    const int wave = t >> 6;
    const int l    = t & 63;
    const int sub  = l >> 4;      // edge-row within group of 4 (0..3)
    const int lane = l & 15;      // column group: float8 = 32B per lane

    for (int s = wave; s < SEGS; s += 4) {
        const int n = base + s;
        if (n >= N) break;                 // wave-uniform
        const int start = sOff[s];
        const int end   = sOff[s + 1];

        float4 a0 = make_float4(0.f, 0.f, 0.f, 0.f);
        float4 a1 = make_float4(0.f, 0.f, 0.f, 0.f);
        for (int e = start + sub; e < end; e += 4) {
            const float4* p = x4 + (size_t)e * D4 + lane * 2;
            float4 v0 = p[0];
            float4 v1 = p[1];
            a0.x += v0.x; a0.y += v0.y; a0.z += v0.z; a0.w += v0.w;
            a1.x += v1.x; a1.y += v1.y; a1.z += v1.z; a1.w += v1.w;
        }

        // merge the 4 sub-rows: lanes l, l^16, l^32, l^48
        a0.x += __shfl_xor(a0.x, 16, 64);
        a0.y += __shfl_xor(a0.y, 16, 64);
        a0.z += __shfl_xor(a0.z, 16, 64);
        a0.w += __shfl_xor(a0.w, 16, 64);
        a1.x += __shfl_xor(a1.x, 16, 64);
        a1.y += __shfl_xor(a1.y, 16, 64);
        a1.z += __shfl_xor(a1.z, 16, 64);
        a1.w += __shfl_xor(a1.w, 16, 64);

        a0.x += __shfl_xor(a0.x, 32, 64);
        a0.y += __shfl_xor(a0.y, 32, 64);
        a0.z += __shfl_xor(a0.z, 32, 64);
        a0.w += __shfl_xor(a0.w, 32, 64);
        a1.x += __shfl_xor(a1.x, 32, 64);
        a1.y += __shfl_xor(a1.y, 32, 64);
        a1.z += __shfl_xor(a1.z, 32, 64);
        a1.w += __shfl_xor(a1.w, 32, 64);

        if (sub == 0) {
            int c = end - start;
            float inv = 1.0f / (float)(c > 0 ? c : 1);   // clamp(count, 1)
            a0.x *= inv; a0.y *= inv; a0.z *= inv; a0.w *= inv;
            a1.x *= inv; a1.y *= inv; a1.z *= inv; a1.w *= inv;
            float4* o = out4 + (size_t)n * D4 + lane * 2;
            o[0] = a0;
            o[1] = a1;
        }
    }
}

extern "C" void kernel_launch(void* const* d_in, const int* in_sizes, int n_in,
                              void* d_out, int out_size, void* d_ws, size_t ws_size,
                              hipStream_t stream) {
    const float* x     = (const float*)d_in[0];
    const int*   index = (const int*)d_in[1];

    const int E = in_sizes[1];            // 640000
    const int N = out_size / 128;         // 100000

    int blocks = (N + SEGS - 1) / SEGS;   // 1563 -> whole grid co-resident
    scatter_mean_blk<<<blocks, 256, 0, stream>>>(
        (const float4*)x, index, (float4*)d_out, E, N);
}